// Round 1
// baseline (224.556 us; speedup 1.0000x reference)
//
#include <hip/hip_runtime.h>

// Problem constants (from reference): B=4, S=2048, D=1024, G=4 -> NG=256, NC=16
constexpr int B_ = 4;
constexpr int S_ = 2048;
constexpr int D_ = 1024;
constexpr int G_ = 4;
constexpr int NG_ = D_ / G_;       // 256
constexpr int NC_ = 1 << G_;       // 16
constexpr int NGROUPS = B_ * S_ * NG_;   // 2,097,152

// One thread per group of G=4 elements.
// weights = softmax((2*cross + gumbel)/tau)  [z^2 and |c|^2 are uniform shifts]
// quantized[j] = sum_c w[c] * cb[c][j]
__global__ __launch_bounds__(256) void gumbel_quant_kernel(
    const float* __restrict__ x,        // [B,S,D]
    const float* __restrict__ gumbel,   // [B,S,NG,NC]
    const float* __restrict__ codebook, // [NC,G]
    const float* __restrict__ log_temp, // scalar
    float* __restrict__ out)            // [B,S,D]
{
    const int idx = blockIdx.x * blockDim.x + threadIdx.x;
    if (idx >= NGROUPS) return;

    // tau = clip(exp(log_temp), 0.05, 5.0); uniform across all threads
    float tau = __expf(log_temp[0]);
    tau = fminf(fmaxf(tau, 0.05f), 5.0f);
    const float inv_tau = 1.0f / tau;

    // Codebook: 64 uniform floats -> scalar loads, broadcast to all lanes.
    float cb[NC_][G_];
#pragma unroll
    for (int c = 0; c < NC_; ++c)
#pragma unroll
        for (int j = 0; j < G_; ++j)
            cb[c][j] = codebook[c * G_ + j];

    // Group input: one coalesced float4 per lane.
    const float4 xg = reinterpret_cast<const float4*>(x)[idx];
    const float xs[G_] = {xg.x, xg.y, xg.z, xg.w};

    // Gumbel noise: 16 floats = 4 float4 loads per lane.
    const float4* gp = reinterpret_cast<const float4*>(gumbel) + (size_t)idx * 4;
    float4 gq0 = gp[0], gq1 = gp[1], gq2 = gp[2], gq3 = gp[3];
    const float gv[NC_] = {gq0.x, gq0.y, gq0.z, gq0.w,
                           gq1.x, gq1.y, gq1.z, gq1.w,
                           gq2.x, gq2.y, gq2.z, gq2.w,
                           gq3.x, gq3.y, gq3.z, gq3.w};

    // vals[c] = (2*cross[c] + gumbel[c]) / tau, track max for stable softmax
    float vals[NC_];
    float m = -INFINITY;
#pragma unroll
    for (int c = 0; c < NC_; ++c) {
        float cross = cb[c][0] * xs[0];
        cross = fmaf(cb[c][1], xs[1], cross);
        cross = fmaf(cb[c][2], xs[2], cross);
        cross = fmaf(cb[c][3], xs[3], cross);
        const float v = fmaf(2.0f, cross, gv[c]) * inv_tau;
        vals[c] = v;
        m = fmaxf(m, v);
    }

    // exp + sum
    float w[NC_];
    float sum = 0.0f;
#pragma unroll
    for (int c = 0; c < NC_; ++c) {
        const float e = __expf(vals[c] - m);
        w[c] = e;
        sum += e;
    }
    const float inv_sum = 1.0f / sum;

    // quantized[j] = (sum_c w[c]*cb[c][j]) / sum
    float q[G_] = {0.0f, 0.0f, 0.0f, 0.0f};
#pragma unroll
    for (int c = 0; c < NC_; ++c) {
#pragma unroll
        for (int j = 0; j < G_; ++j)
            q[j] = fmaf(w[c], cb[c][j], q[j]);
    }

    float4 o;
    o.x = q[0] * inv_sum;
    o.y = q[1] * inv_sum;
    o.z = q[2] * inv_sum;
    o.w = q[3] * inv_sum;
    reinterpret_cast<float4*>(out)[idx] = o;
}

extern "C" void kernel_launch(void* const* d_in, const int* in_sizes, int n_in,
                              void* d_out, int out_size, void* d_ws, size_t ws_size,
                              hipStream_t stream) {
    const float* x        = (const float*)d_in[0];
    const float* gumbel   = (const float*)d_in[1];
    const float* codebook = (const float*)d_in[2];
    const float* log_temp = (const float*)d_in[3];
    float* out = (float*)d_out;

    constexpr int block = 256;
    constexpr int grid = (NGROUPS + block - 1) / block;  // 8192 blocks
    gumbel_quant_kernel<<<grid, block, 0, stream>>>(x, gumbel, codebook, log_temp, out);
}

// Round 2
// 222.927 us; speedup vs baseline: 1.0073x; 1.0073x over previous
//
#include <hip/hip_runtime.h>

// Problem constants (from reference): B=4, S=2048, D=1024, G=4 -> NG=256, NC=16
constexpr int B_ = 4;
constexpr int S_ = 2048;
constexpr int D_ = 1024;
constexpr int G_ = 4;
constexpr int NG_ = D_ / G_;            // 256
constexpr int NC_ = 1 << G_;            // 16
constexpr int NGROUPS = B_ * S_ * NG_;  // 2,097,152

// One thread per group of G=4 elements; 256 groups per block.
// weights = softmax((2*cross + gumbel)/tau)  [z^2 and |c|^2 are uniform shifts
// across the 16 codewords -> cancel in softmax]
// quantized[j] = sum_c w[c] * cb[c][j]
//
// Gumbel (16 floats/group = 64 B/group) is staged through LDS so the global
// loads are lane-contiguous float4s (per-instruction coalesced). LDS layout
// uses a group-stride of 5 float4s: both the scatter-write banks
// (20*(t>>2)+4*(t&3))%32 and the gather-read banks (20*t+4*c4)%32 spread
// ~uniformly over all 32 banks -> near-conflict-free ds_*_b128.
__global__ __launch_bounds__(256) void gumbel_quant_kernel(
    const float* __restrict__ x,        // [B,S,D]
    const float* __restrict__ gumbel,   // [B,S,NG,NC]
    const float* __restrict__ codebook, // [NC,G]
    const float* __restrict__ log_temp, // scalar
    float* __restrict__ out)            // [B,S,D]
{
    __shared__ float4 lds[256 * 5];     // 20 KiB: 256 groups x 4 float4s, stride 5

    const int t = threadIdx.x;
    const int block0 = blockIdx.x * 256;          // first group of this block

    // ---- Phase 1: coalesced gumbel load -> LDS transpose store ----
    // Block's gumbel region: 256 groups * 4 float4s = 1024 float4s.
    const float4* gf4 = reinterpret_cast<const float4*>(gumbel) + (size_t)block0 * 4;
#pragma unroll
    for (int k = 0; k < 4; ++k) {
        const int e = k * 256 + t;                // float4 index within block region
        const float4 v = gf4[e];                  // lane-contiguous: perfectly coalesced
        const int g  = e >> 2;                    // group within block (= 64k + t/4)
        const int c4 = e & 3;                     // which float4 of the group (= t&3)
        lds[g * 5 + c4] = v;
    }

    // x: one coalesced float4 per lane (issued before the barrier to overlap)
    const float4 xg = reinterpret_cast<const float4*>(x)[block0 + t];
    const float xs[G_] = {xg.x, xg.y, xg.z, xg.w};

    // Codebook: 64 uniform floats -> scalar loads, broadcast to all lanes.
    float cb[NC_][G_];
#pragma unroll
    for (int c = 0; c < NC_; ++c)
#pragma unroll
        for (int j = 0; j < G_; ++j)
            cb[c][j] = codebook[c * G_ + j];

    // tau = clip(exp(log_temp), 0.05, 5.0); uniform across all threads
    float tau = __expf(log_temp[0]);
    tau = fminf(fmaxf(tau, 0.05f), 5.0f);
    const float inv_tau = 1.0f / tau;

    __syncthreads();

    // ---- Phase 2: conflict-free LDS gather of this thread's 16 gumbels ----
    float gv[NC_];
#pragma unroll
    for (int c4 = 0; c4 < 4; ++c4) {
        const float4 v = lds[t * 5 + c4];
        gv[c4 * 4 + 0] = v.x;
        gv[c4 * 4 + 1] = v.y;
        gv[c4 * 4 + 2] = v.z;
        gv[c4 * 4 + 3] = v.w;
    }

    // vals[c] = (2*cross[c] + gumbel[c]) / tau, track max for stable softmax
    float vals[NC_];
    float m = -INFINITY;
#pragma unroll
    for (int c = 0; c < NC_; ++c) {
        float cross = cb[c][0] * xs[0];
        cross = fmaf(cb[c][1], xs[1], cross);
        cross = fmaf(cb[c][2], xs[2], cross);
        cross = fmaf(cb[c][3], xs[3], cross);
        const float v = fmaf(2.0f, cross, gv[c]) * inv_tau;
        vals[c] = v;
        m = fmaxf(m, v);
    }

    // exp + sum
    float w[NC_];
    float sum = 0.0f;
#pragma unroll
    for (int c = 0; c < NC_; ++c) {
        const float e = __expf(vals[c] - m);
        w[c] = e;
        sum += e;
    }
    const float inv_sum = 1.0f / sum;

    // quantized[j] = (sum_c w[c]*cb[c][j]) / sum
    float q[G_] = {0.0f, 0.0f, 0.0f, 0.0f};
#pragma unroll
    for (int c = 0; c < NC_; ++c) {
#pragma unroll
        for (int j = 0; j < G_; ++j)
            q[j] = fmaf(w[c], cb[c][j], q[j]);
    }

    float4 o;
    o.x = q[0] * inv_sum;
    o.y = q[1] * inv_sum;
    o.z = q[2] * inv_sum;
    o.w = q[3] * inv_sum;
    reinterpret_cast<float4*>(out)[block0 + t] = o;
}

extern "C" void kernel_launch(void* const* d_in, const int* in_sizes, int n_in,
                              void* d_out, int out_size, void* d_ws, size_t ws_size,
                              hipStream_t stream) {
    const float* x        = (const float*)d_in[0];
    const float* gumbel   = (const float*)d_in[1];
    const float* codebook = (const float*)d_in[2];
    const float* log_temp = (const float*)d_in[3];
    float* out = (float*)d_out;

    constexpr int block = 256;
    constexpr int grid = NGROUPS / block;   // 8192 blocks, 256 groups each
    gumbel_quant_kernel<<<grid, block, 0, stream>>>(x, gumbel, codebook, log_temp, out);
}